// Round 1
// baseline (1293.238 us; speedup 1.0000x reference)
//
#include <hip/hip_runtime.h>

// EdgeAggregate: out[E,64] = segment_sum(feat[nbr[:,1]], nbr[:,0]) @ K[64,64] + bias
// E=500000, P=4000000, D=U=64 (sizes derived from in_sizes at launch).

#define FEAT_D 64

// One wave (64 lanes) per pair: lane d handles feature dim d.
// pair index is forced wave-uniform so nbr loads become s_load.
__global__ __launch_bounds__(256) void ea_scatter(
    const float* __restrict__ feat, const int* __restrict__ nbr,
    float* __restrict__ agg, int P)
{
    const int lane = threadIdx.x & 63;
    const int pair = __builtin_amdgcn_readfirstlane(
        (int)blockIdx.x * 4 + ((int)threadIdx.x >> 6));
    if (pair < P) {
        const int dst = nbr[2 * pair + 0];
        const int src = nbr[2 * pair + 1];
        const float v = feat[(size_t)src * FEAT_D + lane];
        atomicAdd(&agg[(size_t)dst * FEAT_D + lane], v);
    }
}

// In-place row transform: row_out = row_in @ K + bias.
// Lane u holds K column u in 64 VGPRs; row elements are wave-uniform scalar
// loads -> inner loop is 64x v_fmac_f32 (one SGPR operand each), no LDS.
__global__ __launch_bounds__(256) void ea_transform(
    float* __restrict__ io, const float* __restrict__ Kmat,
    const float* __restrict__ bias, int E)
{
    const int lane = threadIdx.x & 63;

    float kcol[FEAT_D];
#pragma unroll
    for (int d = 0; d < FEAT_D; ++d) kcol[d] = Kmat[d * FEAT_D + lane];
    const float b = bias[lane];

    const int wv = __builtin_amdgcn_readfirstlane(
        (int)blockIdx.x * 4 + ((int)threadIdx.x >> 6));
    const int nw = (int)gridDim.x * 4;

    for (int e = wv; e < E; e += nw) {
        const float* __restrict__ row = io + (size_t)e * FEAT_D;
        float acc = b;
#pragma unroll
        for (int d = 0; d < FEAT_D; ++d) acc += row[d] * kcol[d];
        io[(size_t)e * FEAT_D + lane] = acc;
    }
}

extern "C" void kernel_launch(void* const* d_in, const int* in_sizes, int n_in,
                              void* d_out, int out_size, void* d_ws, size_t ws_size,
                              hipStream_t stream)
{
    const float* feat = (const float*)d_in[0];
    const int*   nbr  = (const int*)d_in[1];
    const float* Kmat = (const float*)d_in[2];
    const float* bias = (const float*)d_in[3];
    float* out = (float*)d_out;

    const int E = in_sizes[0] / FEAT_D;   // 500000
    const int P = in_sizes[1] / 2;        // 4000000

    // Zero the accumulator (d_out doubles as the [E,64] aggregation buffer).
    hipMemsetAsync(d_out, 0, (size_t)out_size * sizeof(float), stream);

    // Scatter-add: one wave per pair.
    const int sblocks = (P + 3) / 4;      // 4 waves per 256-thread block
    ea_scatter<<<sblocks, 256, 0, stream>>>(feat, nbr, out, P);

    // In-place linear transform, grid-stride over rows (8192 waves).
    ea_transform<<<2048, 256, 0, stream>>>(out, Kmat, bias, E);
}

// Round 2
// 981.516 us; speedup vs baseline: 1.3176x; 1.3176x over previous
//
#include <hip/hip_runtime.h>

// EdgeAggregate: out[E,64] = segment_sum(feat[nbr[:,1]], nbr[:,0]) @ K[64,64] + bias
// Strategy: device-built CSR (no f32 atomics -- they execute memory-side at
// ~295 G ops/s on MI355X, measured R1), then one wave per dst row gathers +
// reduces in registers and applies the 64x64 transform via a per-wave LDS
// transpose (fused; no 256 MB intermediate round-trip).

#define FD 64

// ---------------- CSR pipeline ----------------

__global__ __launch_bounds__(256) void k_hist(const int* __restrict__ nbr,
                                              int* __restrict__ cnt, int P) {
    int p = blockIdx.x * 256 + threadIdx.x;
    if (p < P) atomicAdd(&cnt[nbr[2 * p]], 1);
}

// block b sums cnt[b*1024 .. b*1024+1023] -> bsum[b]
__global__ __launch_bounds__(256) void k_blocksum(const int* __restrict__ cnt,
                                                  int* __restrict__ bsum, int E) {
    int base = blockIdx.x * 1024;
    int t = threadIdx.x;
    int s = 0;
#pragma unroll
    for (int j = 0; j < 4; ++j) {
        int e = base + t + j * 256;
        if (e < E) s += cnt[e];
    }
    for (int off = 32; off; off >>= 1) s += __shfl_down(s, off, 64);
    __shared__ int wsum[4];
    int wid = t >> 6, lane = t & 63;
    if (lane == 0) wsum[wid] = s;
    __syncthreads();
    if (t == 0) bsum[blockIdx.x] = wsum[0] + wsum[1] + wsum[2] + wsum[3];
}

// single block: exclusive scan of bsum[0..NB), NB <= 1024, in place
__global__ __launch_bounds__(1024) void k_scan_bsum(int* bsum, int NB) {
    __shared__ int s[1024];
    int t = threadIdx.x;
    s[t] = (t < NB) ? bsum[t] : 0;
    __syncthreads();
    int orig = s[t];
    for (int off = 1; off < 1024; off <<= 1) {
        int v = (t >= off) ? s[t - off] : 0;
        __syncthreads();
        s[t] += v;
        __syncthreads();
    }
    if (t < NB) bsum[t] = s[t] - orig;  // exclusive
}

// block b: exclusive-scan its 1024 counts (+ block offset), write offs[] and
// init cursor cur[] = offs[]. cnt and cur may alias (each element read by the
// same thread before it is overwritten).
__global__ __launch_bounds__(256) void k_scan_write(const int* __restrict__ cnt,
                                                    const int* __restrict__ boff,
                                                    int* __restrict__ offs,
                                                    int* __restrict__ cur,
                                                    int E) {
    __shared__ int tsum[256];
    int b = blockIdx.x, t = threadIdx.x;
    int base = b * 1024 + t * 4;
    int c[4];
#pragma unroll
    for (int j = 0; j < 4; ++j) {
        int e = base + j;
        c[j] = (e < E) ? cnt[e] : 0;
    }
    int local = c[0] + c[1] + c[2] + c[3];
    tsum[t] = local;
    __syncthreads();
    for (int off = 1; off < 256; off <<= 1) {
        int v = (t >= off) ? tsum[t - off] : 0;
        __syncthreads();
        tsum[t] += v;
        __syncthreads();
    }
    int run = tsum[t] - local + boff[b];  // exclusive prefix for base+0
#pragma unroll
    for (int j = 0; j < 4; ++j) {
        int e = base + j;
        if (e < E) {
            offs[e] = run;
            cur[e] = run;
            run += c[j];
            if (e == E - 1) offs[E] = run;  // == P
        }
    }
}

__global__ __launch_bounds__(256) void k_build(const int* __restrict__ nbr,
                                               int* __restrict__ cur,
                                               int* __restrict__ csr, int P) {
    int p = blockIdx.x * 256 + threadIdx.x;
    if (p < P) {
        int dst = nbr[2 * p + 0];
        int src = nbr[2 * p + 1];
        int pos = atomicAdd(&cur[dst], 1);
        csr[pos] = src;
    }
}

// One wave per dst row (grid-stride). lane = feature dim d during the gather,
// lane = output unit u after the per-wave LDS transpose. K column u lives in
// 64 VGPRs, loaded once per wave.
__global__ __launch_bounds__(256) void k_agg(const float* __restrict__ feat,
                                             const int* __restrict__ offs,
                                             const int* __restrict__ csr,
                                             const float* __restrict__ Kmat,
                                             const float* __restrict__ bias,
                                             float* __restrict__ out, int E) {
    __shared__ float xr[4 * FD];
    const int lane = threadIdx.x & 63;
    const int wid = threadIdx.x >> 6;

    float kcol[FD];
#pragma unroll
    for (int d = 0; d < FD; ++d) kcol[d] = Kmat[d * FD + lane];
    const float b = bias[lane];

    const int wv = __builtin_amdgcn_readfirstlane((int)blockIdx.x * 4 + wid);
    const int nw = (int)gridDim.x * 4;
    float* const xw = &xr[wid * FD];

    for (int e = wv; e < E; e += nw) {
        const int beg = offs[e], end = offs[e + 1];
        float acc = 0.f;
        int i = beg;
        for (; i + 1 < end; i += 2) {
            int s0 = csr[i], s1 = csr[i + 1];
            float v0 = feat[(size_t)s0 * FD + lane];
            float v1 = feat[(size_t)s1 * FD + lane];
            acc += v0;
            acc += v1;
        }
        if (i < end) acc += feat[(size_t)csr[i] * FD + lane];

        // transpose through private LDS strip (same wave writes then reads;
        // compiler orders via lgkmcnt, no barrier needed)
        xw[lane] = acc;
        float o = b;
        const float4* xp = (const float4*)xw;
#pragma unroll
        for (int j = 0; j < FD / 4; ++j) {
            float4 q = xp[j];
            o += q.x * kcol[4 * j + 0] + q.y * kcol[4 * j + 1] +
                 q.z * kcol[4 * j + 2] + q.w * kcol[4 * j + 3];
        }
        out[(size_t)e * FD + lane] = o;
    }
}

// ---------------- fallback (round-1 path) ----------------

__global__ __launch_bounds__(256) void ea_scatter(const float* __restrict__ feat,
                                                  const int* __restrict__ nbr,
                                                  float* __restrict__ agg, int P) {
    const int lane = threadIdx.x & 63;
    const int pair = __builtin_amdgcn_readfirstlane(
        (int)blockIdx.x * 4 + ((int)threadIdx.x >> 6));
    if (pair < P) {
        const int dst = nbr[2 * pair + 0];
        const int src = nbr[2 * pair + 1];
        atomicAdd(&agg[(size_t)dst * FD + lane], feat[(size_t)src * FD + lane]);
    }
}

__global__ __launch_bounds__(256) void ea_transform(float* __restrict__ io,
                                                    const float* __restrict__ Kmat,
                                                    const float* __restrict__ bias,
                                                    int E) {
    const int lane = threadIdx.x & 63;
    float kcol[FD];
#pragma unroll
    for (int d = 0; d < FD; ++d) kcol[d] = Kmat[d * FD + lane];
    const float b = bias[lane];
    const int wv = __builtin_amdgcn_readfirstlane(
        (int)blockIdx.x * 4 + ((int)threadIdx.x >> 6));
    const int nw = (int)gridDim.x * 4;
    for (int e = wv; e < E; e += nw) {
        const float* __restrict__ row = io + (size_t)e * FD;
        float acc = b;
#pragma unroll
        for (int d = 0; d < FD; ++d) acc += row[d] * kcol[d];
        io[(size_t)e * FD + lane] = acc;
    }
}

// ---------------- launcher ----------------

extern "C" void kernel_launch(void* const* d_in, const int* in_sizes, int n_in,
                              void* d_out, int out_size, void* d_ws, size_t ws_size,
                              hipStream_t stream) {
    const float* feat = (const float*)d_in[0];
    const int* nbr = (const int*)d_in[1];
    const float* Kmat = (const float*)d_in[2];
    const float* bias = (const float*)d_in[3];
    float* out = (float*)d_out;

    const int E = in_sizes[0] / FD;  // 500000
    const int P = in_sizes[1] / 2;   // 4000000
    const int NB = (E + 1023) / 1024;

    const size_t need = ((size_t)E + (size_t)(E + 1) + 1024 + (size_t)P) * sizeof(int);

    if (ws_size >= need && NB <= 1024) {
        int* cur = (int*)d_ws;        // E ints: counts, then CSR cursor
        int* offs = cur + E;          // E+1 ints
        int* bsum = offs + E + 1;     // 1024 ints
        int* csr = bsum + 1024;       // P ints

        hipMemsetAsync(cur, 0, (size_t)E * sizeof(int), stream);
        k_hist<<<(P + 255) / 256, 256, 0, stream>>>(nbr, cur, P);
        k_blocksum<<<NB, 256, 0, stream>>>(cur, bsum, E);
        k_scan_bsum<<<1, 1024, 0, stream>>>(bsum, NB);
        k_scan_write<<<NB, 256, 0, stream>>>(cur, bsum, offs, cur, E);
        k_build<<<(P + 255) / 256, 256, 0, stream>>>(nbr, cur, csr, P);
        k_agg<<<4096, 256, 0, stream>>>(feat, offs, csr, Kmat, bias, out, E);
    } else {
        // fallback: atomic scatter path (round 1)
        hipMemsetAsync(d_out, 0, (size_t)out_size * sizeof(float), stream);
        ea_scatter<<<(P + 3) / 4, 256, 0, stream>>>(feat, nbr, out, P);
        ea_transform<<<2048, 256, 0, stream>>>(out, Kmat, bias, E);
    }
}